// Round 1
// baseline (304.644 us; speedup 1.0000x reference)
//
#include <hip/hip_runtime.h>

typedef short short8 __attribute__((ext_vector_type(8)));
typedef float f32x4 __attribute__((ext_vector_type(4)));
typedef unsigned short u16x4 __attribute__((ext_vector_type(4)));

constexpr int NB = 16, CIN = 128, LIN = 2048, CO = 256;
constexpr int SL = 2041;                 // output sequence length
constexpr int MT = NB * SL;              // 32656 valid rows
constexpr int MP = 32768;                // padded rows

// ---- workspace layout (bytes, all 256-aligned) ----
constexpr size_t XB_OFF = 0;
constexpr size_t XB_SZ  = (size_t)NB*CIN*LIN*2 + 1024;   // bf16 x + OOB slack
constexpr size_t CW_OFF = XB_OFF + XB_SZ;
constexpr size_t CW_SZ  = (size_t)CO*CIN*8*2;            // conv_w bf16 [256][1024]
constexpr size_t WQ_OFF = CW_OFF + CW_SZ;
constexpr size_t WB_SZ  = (size_t)CO*CO*2;
constexpr size_t WK_OFF = WQ_OFF + WB_SZ;
constexpr size_t WV_OFF = WK_OFF + WB_SZ;
constexpr size_t H_OFF  = WV_OFF + WB_SZ;
constexpr size_t HB_SZ  = (size_t)MP*CO*2;               // 16 MB each
constexpr size_t Q_OFF  = H_OFF + HB_SZ;
constexpr size_t K_OFF  = Q_OFF + HB_SZ;
constexpr size_t VT_OFF = K_OFF + HB_SZ;                 // v transposed [256][16][2048]

__device__ inline unsigned short f2bf(float f) {
  union { float f; unsigned int u; } v; v.f = f;
  unsigned int r = v.u + 0x7fffu + ((v.u >> 16) & 1u);
  return (unsigned short)(r >> 16);
}

#if defined(__has_builtin)
#if __has_builtin(__builtin_amdgcn_global_load_lds)
#define HAVE_GLDS 1
#endif
#endif

__device__ inline void gld16(const unsigned short* g, void* l) {
#ifdef HAVE_GLDS
  __builtin_amdgcn_global_load_lds(
      (const __attribute__((address_space(1))) void*)g,
      (__attribute__((address_space(3))) void*)l, 16, 0, 0);
#else
  *(short8*)l = *(const short8*)g;
#endif
}

// ---------------- fp32 -> bf16 convert ----------------
__global__ void cvt_kernel(const float* __restrict__ src,
                           unsigned short* __restrict__ dst, int count) {
  int i = (blockIdx.x * 256 + threadIdx.x) * 4;
  if (i < count) {
    float4 v = *(const float4*)(src + i);
    u16x4 r;
    r.x = f2bf(v.x); r.y = f2bf(v.y); r.z = f2bf(v.z); r.w = f2bf(v.w);
    *(u16x4*)(dst + i) = r;
  }
}

// ---------------- conv as implicit GEMM ----------------
// grid (16 s-tiles, 16 n, 2 d-tiles), 256 threads. C[m=n*SL+s][co] = relu(sum + b)
__global__ __launch_bounds__(256) void conv_gemm(
    const unsigned short* __restrict__ xb,   // [16][128][2048] bf16
    const unsigned short* __restrict__ wb,   // [256][1024] bf16 (kk = ci*8+kp)
    const float* __restrict__ bias,          // [256]
    unsigned short* __restrict__ h)          // [MP][256] bf16
{
  __shared__ unsigned short sX[128 * 144];   // x window [ci][144 s], 36 KB
  __shared__ unsigned short sB[128 * 32];    // weight chunk, 8 KB
  const int tid = threadIdx.x;
  const int w = tid >> 6, lane = tid & 63, quad = lane >> 4, l16 = lane & 15;
  const int n  = blockIdx.y;
  const int s0 = blockIdx.x * 128;
  const int d0 = blockIdx.z * 128;

  { // stage x window once: 128 rows x 288 B = 2304 x 16 B
    const unsigned short* xbase = xb + (size_t)n * CIN * LIN;
    #pragma unroll
    for (int i = 0; i < 9; ++i) {
      int off = (i * 256 + tid) * 16;          // byte offset into sX
      int ci  = off / 288;
      int rem = off - ci * 288;
      gld16(xbase + (size_t)ci * LIN + s0 + (rem >> 1), ((char*)sX) + off);
    }
  }

  f32x4 acc[2][8];
  #pragma unroll
  for (int i = 0; i < 2; ++i)
    #pragma unroll
    for (int j = 0; j < 8; ++j) acc[i][j] = (f32x4){0.f, 0.f, 0.f, 0.f};

  for (int kc = 0; kc < 32; ++kc) {
    __syncthreads();   // protect sB readers of previous chunk; completes X on kc=0
    #pragma unroll
    for (int i2 = 0; i2 < 2; ++i2) {
      int off = (i2 * 256 + tid) * 16;
      int row = off >> 6, kg = (off >> 4) & 3;
      gld16(wb + (size_t)(d0 + row) * 1024 + kc * 32 + kg * 8, ((char*)sB) + off);
    }
    __syncthreads();

    short8 bfr[8];
    #pragma unroll
    for (int j = 0; j < 8; ++j)
      bfr[j] = *(const short8*)(sB + (j * 16 + l16) * 32 + quad * 8);

    #pragma unroll
    for (int i = 0; i < 2; ++i) {
      int srow = w * 32 + i * 16 + l16;
      short8 afr;   // unaligned (2B) read: rows shift by 1 elem (stride-1 conv)
      __builtin_memcpy(&afr, sX + (kc * 4 + quad) * 144 + srow, 16);
      #pragma unroll
      for (int j = 0; j < 8; ++j)
        acc[i][j] = __builtin_amdgcn_mfma_f32_16x16x32_bf16(afr, bfr[j], acc[i][j], 0, 0, 0);
    }
  }

  #pragma unroll
  for (int i = 0; i < 2; ++i)
    #pragma unroll
    for (int j = 0; j < 8; ++j) {
      int col = d0 + j * 16 + l16;
      float bv = bias[col];
      #pragma unroll
      for (int jj = 0; jj < 4; ++jj) {
        int s = s0 + w * 32 + i * 16 + quad * 4 + jj;
        if (s < SL) {
          float val = fmaxf(acc[i][j][jj] + bv, 0.f);
          h[(size_t)(n * SL + s) * CO + col] = f2bf(val);
        }
      }
    }
}

// ---------------- q/k/v linear GEMMs ----------------
// grid (256 m-tiles, 2 d-tiles, 3 {q,k,v}), 256 threads
__global__ __launch_bounds__(256) void lin_gemm(
    const unsigned short* __restrict__ A,    // h [MP][256]
    const unsigned short* __restrict__ Bq, const unsigned short* __restrict__ Bk,
    const unsigned short* __restrict__ Bv,
    const float* __restrict__ biq, const float* __restrict__ bik,
    const float* __restrict__ biv,
    unsigned short* __restrict__ qb, unsigned short* __restrict__ kb,
    unsigned short* __restrict__ vtb)
{
  __shared__ unsigned short sA[128 * 32];
  __shared__ unsigned short sB[128 * 32];
  const int tid = threadIdx.x;
  const int w = tid >> 6, lane = tid & 63, quad = lane >> 4, l16 = lane & 15;
  const int m0 = blockIdx.x * 128, d0 = blockIdx.y * 128, z = blockIdx.z;
  const unsigned short* B = (z == 0) ? Bq : (z == 1) ? Bk : Bv;
  const float* bias        = (z == 0) ? biq : (z == 1) ? bik : biv;

  f32x4 acc[2][8];
  #pragma unroll
  for (int i = 0; i < 2; ++i)
    #pragma unroll
    for (int j = 0; j < 8; ++j) acc[i][j] = (f32x4){0.f, 0.f, 0.f, 0.f};

  for (int kc = 0; kc < 8; ++kc) {
    __syncthreads();
    #pragma unroll
    for (int i2 = 0; i2 < 2; ++i2) {
      int off = (i2 * 256 + tid) * 16;
      int row = off >> 6, kg = (off >> 4) & 3;
      gld16(A + (size_t)(m0 + row) * CO + kc * 32 + kg * 8, ((char*)sA) + off);
      gld16(B + (size_t)(d0 + row) * CO + kc * 32 + kg * 8, ((char*)sB) + off);
    }
    __syncthreads();

    short8 afr[2], bfr[8];
    #pragma unroll
    for (int i = 0; i < 2; ++i)
      afr[i] = *(const short8*)(sA + (w * 32 + i * 16 + l16) * 32 + quad * 8);
    #pragma unroll
    for (int j = 0; j < 8; ++j)
      bfr[j] = *(const short8*)(sB + (j * 16 + l16) * 32 + quad * 8);
    #pragma unroll
    for (int i = 0; i < 2; ++i)
      #pragma unroll
      for (int j = 0; j < 8; ++j)
        acc[i][j] = __builtin_amdgcn_mfma_f32_16x16x32_bf16(afr[i], bfr[j], acc[i][j], 0, 0, 0);
  }

  #pragma unroll
  for (int i = 0; i < 2; ++i)
    #pragma unroll
    for (int j = 0; j < 8; ++j) {
      int col = d0 + j * 16 + l16;
      float bv = bias[col];
      #pragma unroll
      for (int jj = 0; jj < 4; ++jj) {
        int m = m0 + w * 32 + i * 16 + quad * 4 + jj;
        float val = acc[i][j][jj] + bv;
        if (z < 2) {
          ((z == 0) ? qb : kb)[(size_t)m * CO + col] = f2bf(val);
        } else if (m < MT) {
          int nn = m / SL, ss = m - nn * SL;
          vtb[(size_t)col * MP + nn * 2048 + ss] = f2bf(val);  // transposed, per-n padded
        }
      }
    }
}

// ---------------- fused sigmoid attention ----------------
// grid (32 s-tiles of 64, 16 n), 256 threads (4 waves; wave w owns s rows w*16..w*16+15)
__global__ __launch_bounds__(256) void attn_kernel(
    const unsigned short* __restrict__ qb,   // [MP][256]
    const unsigned short* __restrict__ kb,   // [MP][256]
    const unsigned short* __restrict__ vtb,  // [256][16][2048]
    float* __restrict__ out)                 // [16][256][2041]
{
  __shared__ unsigned short sKV[16384];  // 32 KB: K [8][64][32] then V [2][256][32]
  __shared__ unsigned short sP[4096];    // 8 KB: P [64 s][64 t]
  const int tid = threadIdx.x;
  const int w = tid >> 6, lane = tid & 63, quad = lane >> 4, l16 = lane & 15;
  const int n = blockIdx.y, s0 = blockIdx.x * 64;
  const int srow = w * 16 + l16;

  // Q fragments in registers for the whole t-loop
  short8 qf[8];
  {
    const unsigned short* qp = qb + (size_t)(n * SL + s0 + srow) * CO + quad * 8;
    #pragma unroll
    for (int c = 0; c < 8; ++c) qf[c] = *(const short8*)(qp + c * 32);
  }

  f32x4 o[16];
  #pragma unroll
  for (int jd = 0; jd < 16; ++jd) o[jd] = (f32x4){0.f, 0.f, 0.f, 0.f};

  for (int t0 = 0; t0 < 2048; t0 += 64) {
    __syncthreads();   // prev iter PV readers done with sKV
    #pragma unroll
    for (int i = 0; i < 8; ++i) {          // stage K tile [8 c-chunks][64 t][32]
      int u = (i * 256 + tid) * 8;
      int c = u >> 11, rem = u & 2047, trow = rem >> 5, kg = (rem >> 3) & 3;
      gld16(kb + (size_t)(n * SL + t0 + trow) * CO + c * 32 + kg * 8,
            ((char*)sKV) + u * 2);
    }
    __syncthreads();

    f32x4 sa[4];
    #pragma unroll
    for (int j = 0; j < 4; ++j) sa[j] = (f32x4){0.f, 0.f, 0.f, 0.f};
    #pragma unroll
    for (int c = 0; c < 8; ++c)
      #pragma unroll
      for (int j = 0; j < 4; ++j) {
        short8 bfr = *(const short8*)(sKV + c * 2048 + (j * 16 + l16) * 32 + quad * 8);
        sa[j] = __builtin_amdgcn_mfma_f32_16x16x32_bf16(qf[c], bfr, sa[j], 0, 0, 0);
      }

    // sigmoid(x/16), mask invalid t, C-layout -> A-layout via LDS
    #pragma unroll
    for (int j = 0; j < 4; ++j)
      #pragma unroll
      for (int jj = 0; jj < 4; ++jj) {
        int t = t0 + j * 16 + l16;
        float p = 1.f / (1.f + __expf(-sa[j][jj] * 0.0625f));
        sP[(w * 16 + quad * 4 + jj) * 64 + j * 16 + l16] =
            (t < SL) ? f2bf(p) : (unsigned short)0;
      }
    __syncthreads();   // sP ready AND all waves done reading K

    #pragma unroll
    for (int i = 0; i < 8; ++i) {          // stage V tile [2 t-chunks][256 d][32]
      int u = (i * 256 + tid) * 8;
      int tc = u >> 13, rem = u & 8191, drow = rem >> 5, kg = (rem >> 3) & 3;
      gld16(vtb + (size_t)drow * MP + n * 2048 + t0 + tc * 32 + kg * 8,
            ((char*)sKV) + u * 2);
    }
    __syncthreads();

    #pragma unroll
    for (int tc = 0; tc < 2; ++tc) {
      short8 pa = *(const short8*)(sP + (w * 16 + l16) * 64 + tc * 32 + quad * 8);
      #pragma unroll
      for (int jd = 0; jd < 16; ++jd) {
        short8 bv = *(const short8*)(sKV + tc * 8192 + (jd * 16 + l16) * 32 + quad * 8);
        o[jd] = __builtin_amdgcn_mfma_f32_16x16x32_bf16(pa, bv, o[jd], 0, 0, 0);
      }
    }
  }

  #pragma unroll
  for (int jd = 0; jd < 16; ++jd) {
    int d = jd * 16 + l16;
    #pragma unroll
    for (int jj = 0; jj < 4; ++jj) {
      int s = s0 + w * 16 + quad * 4 + jj;
      if (s < SL)
        out[(size_t)n * CO * SL + (size_t)d * SL + s] = o[jd][jj];
    }
  }
}

extern "C" void kernel_launch(void* const* d_in, const int* in_sizes, int n_in,
                              void* d_out, int out_size, void* d_ws, size_t ws_size,
                              hipStream_t stream) {
  const float* x      = (const float*)d_in[0];
  const float* conv_w = (const float*)d_in[1];
  const float* conv_b = (const float*)d_in[2];
  const float* wq     = (const float*)d_in[3];
  const float* bq     = (const float*)d_in[4];
  const float* wk     = (const float*)d_in[5];
  const float* bk     = (const float*)d_in[6];
  const float* wv     = (const float*)d_in[7];
  const float* bv     = (const float*)d_in[8];

  char* ws = (char*)d_ws;
  unsigned short* xb  = (unsigned short*)(ws + XB_OFF);
  unsigned short* cw  = (unsigned short*)(ws + CW_OFF);
  unsigned short* wqb = (unsigned short*)(ws + WQ_OFF);
  unsigned short* wkb = (unsigned short*)(ws + WK_OFF);
  unsigned short* wvb = (unsigned short*)(ws + WV_OFF);
  unsigned short* hb  = (unsigned short*)(ws + H_OFF);
  unsigned short* qb  = (unsigned short*)(ws + Q_OFF);
  unsigned short* kb  = (unsigned short*)(ws + K_OFF);
  unsigned short* vtb = (unsigned short*)(ws + VT_OFF);

  hipLaunchKernelGGL(cvt_kernel, dim3(4096), dim3(256), 0, stream, x, xb, NB * CIN * LIN);
  hipLaunchKernelGGL(cvt_kernel, dim3(256),  dim3(256), 0, stream, conv_w, cw, CO * CIN * 8);
  hipLaunchKernelGGL(cvt_kernel, dim3(64),   dim3(256), 0, stream, wq, wqb, CO * CO);
  hipLaunchKernelGGL(cvt_kernel, dim3(64),   dim3(256), 0, stream, wk, wkb, CO * CO);
  hipLaunchKernelGGL(cvt_kernel, dim3(64),   dim3(256), 0, stream, wv, wvb, CO * CO);

  hipLaunchKernelGGL(conv_gemm, dim3(16, 16, 2), dim3(256), 0, stream, xb, cw, conv_b, hb);
  hipLaunchKernelGGL(lin_gemm,  dim3(256, 2, 3), dim3(256), 0, stream,
                     hb, wqb, wkb, wvb, bq, bk, bv, qb, kb, vtb);
  hipLaunchKernelGGL(attn_kernel, dim3(32, 16), dim3(256), 0, stream,
                     qb, kb, vtb, (float*)d_out);
}